// Round 5
// baseline (128.063 us; speedup 1.0000x reference)
//
#include <hip/hip_runtime.h>
#include <cstddef>
#include <cstdint>

typedef short bf16x8 __attribute__((ext_vector_type(8)));
typedef float f32x4 __attribute__((ext_vector_type(4)));

#define Bsz 256
#define Dsz 512
#define Gsz 64
#define Ksz 512

// ws float offsets
#define WS_DFLAT 0         // [512][256] f32
#define WS_SOFTS 131072    // [256][512] f32 (b-major, flat-k)
#define WS_BNORM 278528    // [256]
#define WS_CNORM 278784    // [512]
#define WS_PSB   279296    // [256][64] bf16
#define WS_ONB   287488    // 2 planes [512][512] bf16
#define WS_ZB    549632    // 2 planes [256][512] bf16

#define ONB_STRIDE 262144  // ushorts per plane
#define ZB_STRIDE  131072  // ushorts per plane

// out float offsets
#define OUT_QMU  0
#define OUT_QSIG 33554432
#define OUT_DBG  67108864
#define OUT_DIST 67125248

__device__ __forceinline__ unsigned short f2bf(float f) {
  unsigned int u = __float_as_uint(f);
  u = (u + 0x7FFFu + ((u >> 16) & 1u)) >> 16;
  return (unsigned short)u;
}
__device__ __forceinline__ float bf2f(unsigned short h) {
  return __uint_as_float(((unsigned int)h) << 16);
}

// ---------- K1: prep. blocks 0..511: codebook row k -> cnorm + onb planes.
//                blocks 512..767: batch row b -> bnorm + zb planes. ----------
__global__ __launch_bounds__(256) void k_prep(const float* __restrict__ mu,
                                              const float* __restrict__ ls,
                                              const float* __restrict__ on,
                                              float* __restrict__ ws) {
  int t = threadIdx.x;
  __shared__ float red[256];
  if (blockIdx.x < 512) {
    int k = blockIdx.x;
    float4 v = *(const float4*)(on + (size_t)k * 1024 + 4 * t);
    unsigned short* onb0 = (unsigned short*)(ws + WS_ONB);
    unsigned short* onb1 = onb0 + ONB_STRIDE;
    *(ushort2*)&onb0[(size_t)k * 512 + 2 * t] = make_ushort2(f2bf(v.x), f2bf(v.z));
    *(ushort2*)&onb1[(size_t)k * 512 + 2 * t] = make_ushort2(f2bf(v.y), f2bf(v.w));
    red[t] = v.x * v.x + v.y * v.y + v.z * v.z + v.w * v.w;
    __syncthreads();
    for (int off = 128; off > 0; off >>= 1) {
      if (t < off) red[t] += red[t + off];
      __syncthreads();
    }
    if (t == 0) ws[WS_CNORM + k] = red[0];
  } else {
    int b = blockIdx.x - 512;
    unsigned short* zb0 = (unsigned short*)(ws + WS_ZB);
    unsigned short* zb1 = zb0 + ZB_STRIDE;
    float part = 0.f;
    for (int d = t; d < Dsz; d += 256) {
      float m = mu[b * Dsz + d];
      float s = expf(ls[b * Dsz + d]);
      zb0[(size_t)b * 512 + d] = f2bf(m);
      zb1[(size_t)b * 512 + d] = f2bf(s);
      part += m * m + s * s;
    }
    red[t] = part;
    __syncthreads();
    for (int off = 128; off > 0; off >>= 1) {
      if (t < off) red[t] += red[t + off];
      __syncthreads();
    }
    if (t == 0) ws[WS_BNORM + b] = red[0];
  }
}

// ---------- K2: d_kb[k][b] = cnorm + bnorm - 2*dot via bf16 MFMA ----------
// grid 256 = kt(32) x bt(8); tile 16k x 32b; wave w owns one K-quarter (256 of 1024).
// Also zeroes OUT_DIST (block 0) for K3's atomics.
__global__ __launch_bounds__(256) void k_dkb(float* __restrict__ ws,
                                             float* __restrict__ out) {
  __shared__ float pl[4][16][33];
  int t = threadIdx.x, l = t & 63, w = t >> 6;
  int lr = l & 15, lh = l >> 4;
  if (blockIdx.x == 0) out[OUT_DIST + t] = 0.f;
  int kt = blockIdx.x >> 3, bt = blockIdx.x & 7;
  int k0 = kt * 16, b0 = bt * 32;
  const unsigned short* Ap =
      (const unsigned short*)(ws + WS_ONB) + (size_t)(w >> 1) * ONB_STRIDE + (size_t)k0 * 512;
  const unsigned short* Bp =
      (const unsigned short*)(ws + WS_ZB) + (size_t)(w >> 1) * ZB_STRIDE + (size_t)b0 * 512;
  int dbase = (w & 1) * 256;

  f32x4 acc[2];
#pragma unroll
  for (int j = 0; j < 2; ++j) { acc[j][0] = 0.f; acc[j][1] = 0.f; acc[j][2] = 0.f; acc[j][3] = 0.f; }

#pragma unroll
  for (int kk = 0; kk < 8; ++kk) {
    int dl = dbase + kk * 32 + lh * 8;
    bf16x8 a0 = *(const bf16x8*)(Ap + (size_t)lr * 512 + dl);
    bf16x8 q0 = *(const bf16x8*)(Bp + (size_t)lr * 512 + dl);
    bf16x8 q1 = *(const bf16x8*)(Bp + (size_t)(lr + 16) * 512 + dl);
    acc[0] = __builtin_amdgcn_mfma_f32_16x16x32_bf16(a0, q0, acc[0], 0, 0, 0);
    acc[1] = __builtin_amdgcn_mfma_f32_16x16x32_bf16(a0, q1, acc[1], 0, 0, 0);
  }

#pragma unroll
  for (int j = 0; j < 2; ++j)
#pragma unroll
    for (int r = 0; r < 4; ++r)
      pl[w][lh * 4 + r][j * 16 + lr] = acc[j][r];
  __syncthreads();

  int r = t >> 4, c = (t & 15) * 2;
  float s0 = pl[0][r][c] + pl[1][r][c] + pl[2][r][c] + pl[3][r][c];
  float s1 = pl[0][r][c + 1] + pl[1][r][c + 1] + pl[2][r][c + 1] + pl[3][r][c + 1];
  float cn = ws[WS_CNORM + k0 + r];
  float2 o = make_float2(cn + ws[WS_BNORM + b0 + c] - 2.f * s0,
                         cn + ws[WS_BNORM + b0 + c + 1] - 2.f * s1);
  *(float2*)&ws[WS_DFLAT + (size_t)(k0 + r) * 256 + b0 + c] = o;
}

// ---------- K3: fused group-softmax (scrambled reshape) + ps softmax + dist atomics ----------
// grid 64 = g; thread t = b.
__global__ __launch_bounds__(256) void k_sm(float* __restrict__ ws,
                                            float* __restrict__ out) {
  int g = blockIdx.x, t = threadIdx.x;
  const float* df = ws + WS_DFLAT;
  int k = 2 * t + (g >> 5);
  int col = (g & 31) << 3;
  const float* p = df + (size_t)k * 256 + col;
  float4 v0 = *(const float4*)p;
  float4 v1 = *(const float4*)(p + 4);
  float d[8] = {v0.x, v0.y, v0.z, v0.w, v1.x, v1.y, v1.z, v1.w};
  float m = d[0];
#pragma unroll
  for (int n = 1; n < 8; ++n) m = fminf(m, d[n]);
  float wv[8], s = 0.f, wd = 0.f;
#pragma unroll
  for (int n = 0; n < 8; ++n) {
    wv[n] = expf(m - d[n]);
    s += wv[n];
    wd += wv[n] * d[n];
  }
  float inv = 1.f / s;
  float* so = ws + WS_SOFTS + (size_t)t * 512 + g * 8;
  *(float4*)so = make_float4(wv[0] * inv, wv[1] * inv, wv[2] * inv, wv[3] * inv);
  *(float4*)(so + 4) = make_float4(wv[4] * inv, wv[5] * inv, wv[6] * inv, wv[7] * inv);
  float dbg = wd * inv;
  out[OUT_DBG + t * 64 + g] = dbg;

  __shared__ float red[256];
  red[t] = dbg;
  __syncthreads();
  for (int off = 128; off > 0; off >>= 1) {
    if (t < off) red[t] = fminf(red[t], red[t + off]);
    __syncthreads();
  }
  float mm = red[0];
  __syncthreads();
  float wp = expf(mm - dbg);
  red[t] = wp;
  __syncthreads();
  for (int off = 128; off > 0; off >>= 1) {
    if (t < off) red[t] += red[t + off];
    __syncthreads();
  }
  float psv = wp / red[0];
  ((unsigned short*)(ws + WS_PSB))[t * 64 + g] = f2bf(psv);
  atomicAdd(&out[OUT_DIST + t], psv * dbg);
}

// ---------- K4: quantised_{mu,sig} via bf16 MFMA, write-bound ----------
// grid 2048 = x(256) x dt(8). C'[d][b] = sum_g S_T[d][g] * ps[b][g].
// NEW: per-wave LDS transpose epilogue. R4's direct stores put 16 lanes at
// 2 KB stride x 64 B partial lines (~16 tx/KB); routing acc through a
// per-wave Cl[16b][72d] tile (same-wave DS ops are in-order, no barrier)
// makes each store instr 4 rows x 256 B contiguous = full-line tx (8/KB),
// matching fillBuffer's measured 6.9 TB/s pattern.
__global__ __launch_bounds__(256) void k_quant(const float* __restrict__ ws,
                                               float* __restrict__ out) {
  __shared__ __align__(16) unsigned short st[2][4096];  // [e][d][g] swizzled, 16 KB
  __shared__ float sxl[576];                            // softs, stride-9 padded
  __shared__ __align__(16) float Cl[4][16][72];         // per-wave transpose pad, 18 KB
  int x = blockIdx.x >> 3, dt = blockIdx.x & 7;
  int dBase = dt * 64;
  int t = threadIdx.x, l = t & 63, w = t >> 6;
  int lr = l & 15, lh = l >> 4;

  // B fragments (ps) straight from global (L2-hit, used once)
  const unsigned short* psb = (const unsigned short*)(ws + WS_PSB);
  bf16x8 bn[4][2];
#pragma unroll
  for (int j = 0; j < 4; ++j)
#pragma unroll
    for (int kk = 0; kk < 2; ++kk)
      bn[j][kk] = *(const bf16x8*)&psb[(size_t)(w * 64 + j * 16 + lr) * 64 + kk * 32 + lh * 8];

  {
    int i0 = t, i1 = t + 256;
    sxl[(i0 >> 3) * 9 + (i0 & 7)] = ws[WS_SOFTS + (size_t)x * 512 + i0];
    sxl[(i1 >> 3) * 9 + (i1 & 7)] = ws[WS_SOFTS + (size_t)x * 512 + i1];
  }
  __syncthreads();

  // build S_T for BOTH planes: thread owns 4 d (dq*4..+3) x 4 g (gq*4..+3)
  int dq = t & 15, gq = t >> 4;
#pragma unroll 1
  for (int e = 0; e < 2; ++e) {
    const unsigned short* ob =
        (const unsigned short*)(ws + WS_ONB) + (size_t)e * ONB_STRIDE + dBase + dq * 4;
    float av[4][4];
#pragma unroll
    for (int gg = 0; gg < 4; ++gg) {
      int g = gq * 4 + gg;
      float a0 = 0.f, a1 = 0.f, a2 = 0.f, a3 = 0.f;
      const unsigned short* rp = ob + (size_t)(g * 8) * 512;
#pragma unroll
      for (int n = 0; n < 8; ++n) {
        ushort4 vv = *(const ushort4*)(rp + (size_t)n * 512);
        float swv = sxl[g * 9 + n];
        a0 += swv * bf2f(vv.x);
        a1 += swv * bf2f(vv.y);
        a2 += swv * bf2f(vv.z);
        a3 += swv * bf2f(vv.w);
      }
      av[gg][0] = a0; av[gg][1] = a1; av[gg][2] = a2; av[gg][3] = a3;
    }
#pragma unroll
    for (int dd = 0; dd < 4; ++dd) {
      int d = dq * 4 + dd;
      ushort4 o = make_ushort4(f2bf(av[0][dd]), f2bf(av[1][dd]), f2bf(av[2][dd]), f2bf(av[3][dd]));
      *(ushort4*)&st[e][(d * 64 + gq * 4) ^ ((d & 7) << 3)] = o;
    }
  }
  __syncthreads();

  float* cl = &Cl[w][0][0];
#pragma unroll 1
  for (int e = 0; e < 2; ++e) {
    bf16x8 am[4][2];
#pragma unroll
    for (int i = 0; i < 4; ++i)
#pragma unroll
      for (int kk = 0; kk < 2; ++kk)
        am[i][kk] = *(const bf16x8*)&st[e][((i * 16 + lr) * 64 + kk * 32 + lh * 8) ^ ((lr & 7) << 3)];

    f32x4 acc[4][4];
#pragma unroll
    for (int i = 0; i < 4; ++i)
#pragma unroll
      for (int j = 0; j < 4; ++j) {
        acc[i][j][0] = 0.f; acc[i][j][1] = 0.f; acc[i][j][2] = 0.f; acc[i][j][3] = 0.f;
      }
#pragma unroll
    for (int kk = 0; kk < 2; ++kk)
#pragma unroll
      for (int i = 0; i < 4; ++i)
#pragma unroll
        for (int j = 0; j < 4; ++j)
          acc[i][j] = __builtin_amdgcn_mfma_f32_16x16x32_bf16(am[i][kk], bn[j][kk], acc[i][j], 0, 0, 0);

    // transpose epilogue: per wave, per 16-b group j:
    //   acc[i][j] (lane holds d=i*16+lh*4..+3 at b_local=lr) -> Cl[lr][d] (b128),
    //   then read Cl[it*4+lh][lr*4..+3] -> store 4 rows x 256 B contiguous.
    float* op = out + (e ? (size_t)OUT_QSIG : (size_t)OUT_QMU) + (size_t)x * (256 * 512);
#pragma unroll 1
    for (int j = 0; j < 4; ++j) {
#pragma unroll
      for (int i = 0; i < 4; ++i)
        *(f32x4*)&cl[lr * 72 + i * 16 + lh * 4] = acc[i][j];
#pragma unroll
      for (int it = 0; it < 4; ++it) {
        f32x4 v = *(const f32x4*)&cl[(it * 4 + lh) * 72 + lr * 4];
        size_t off = (size_t)(w * 64 + j * 16 + it * 4 + lh) * 512 + dBase + lr * 4;
        *(f32x4*)&op[off] = v;
      }
    }
  }
}

extern "C" void kernel_launch(void* const* d_in, const int* in_sizes, int n_in,
                              void* d_out, int out_size, void* d_ws, size_t ws_size,
                              hipStream_t stream) {
  (void)in_sizes; (void)n_in; (void)out_size; (void)ws_size;
  const float* mu = (const float*)d_in[0];
  const float* ls = (const float*)d_in[1];
  const float* on = (const float*)d_in[2];
  float* out = (float*)d_out;
  float* ws = (float*)d_ws;

  k_prep<<<dim3(768), dim3(256), 0, stream>>>(mu, ls, on, ws);
  k_dkb<<<dim3(256), dim3(256), 0, stream>>>(ws, out);
  k_sm<<<dim3(64), dim3(256), 0, stream>>>(ws, out);
  k_quant<<<dim3(2048), dim3(256), 0, stream>>>(ws, out);
}

// Round 6
// 124.242 us; speedup vs baseline: 1.0308x; 1.0308x over previous
//
#include <hip/hip_runtime.h>
#include <cstddef>
#include <cstdint>

typedef short bf16x8 __attribute__((ext_vector_type(8)));
typedef float f32x4 __attribute__((ext_vector_type(4)));

#define Bsz 256
#define Dsz 512
#define Gsz 64
#define Ksz 512

// ws float offsets
#define WS_DFLAT 0         // [512][256] f32
#define WS_SOFTS 131072    // [256][512] f32 (b-major, flat-k)
#define WS_BNORM 278528    // [256]
#define WS_CNORM 278784    // [512]
#define WS_PSB   279296    // [256][64] bf16, FRAGMENT-ORDER (see psb_idx)
#define WS_ONB   287488    // 2 planes [512][512] bf16
#define WS_ZB    549632    // 2 planes [256][512] bf16
#define WS_S     680704    // S[g][x][e*512+d] bf16 = 16.7M ushorts (33.5 MB)

#define ONB_STRIDE 262144  // ushorts per plane
#define ZB_STRIDE  131072  // ushorts per plane
#define WS_S_NEED  ((size_t)WS_S * 4 + 33554432u)

// out float offsets
#define OUT_QMU  0
#define OUT_QSIG 33554432
#define OUT_DBG  67108864
#define OUT_DIST 67125248

__device__ __forceinline__ unsigned short f2bf(float f) {
  unsigned int u = __float_as_uint(f);
  u = (u + 0x7FFFu + ((u >> 16) & 1u)) >> 16;
  return (unsigned short)u;
}
__device__ __forceinline__ float bf2f(unsigned short h) {
  return __uint_as_float(((unsigned int)h) << 16);
}
// fragment-order index for ps bf16: wave w=b>>6 reads [w*4096 + j*1024 + kk*512 + l*8]
__device__ __forceinline__ int psb_idx(int b, int g) {
  return ((b >> 6) << 12) | (((b >> 4) & 3) << 10) | ((g >> 5) << 9) |
         (((g >> 3) & 3) << 7) | ((b & 15) << 3) | (g & 7);
}

// ---------- K1: prep (unchanged from R4) ----------
__global__ __launch_bounds__(256) void k_prep(const float* __restrict__ mu,
                                              const float* __restrict__ ls,
                                              const float* __restrict__ on,
                                              float* __restrict__ ws) {
  int t = threadIdx.x;
  __shared__ float red[256];
  if (blockIdx.x < 512) {
    int k = blockIdx.x;
    float4 v = *(const float4*)(on + (size_t)k * 1024 + 4 * t);
    unsigned short* onb0 = (unsigned short*)(ws + WS_ONB);
    unsigned short* onb1 = onb0 + ONB_STRIDE;
    *(ushort2*)&onb0[(size_t)k * 512 + 2 * t] = make_ushort2(f2bf(v.x), f2bf(v.z));
    *(ushort2*)&onb1[(size_t)k * 512 + 2 * t] = make_ushort2(f2bf(v.y), f2bf(v.w));
    red[t] = v.x * v.x + v.y * v.y + v.z * v.z + v.w * v.w;
    __syncthreads();
    for (int off = 128; off > 0; off >>= 1) {
      if (t < off) red[t] += red[t + off];
      __syncthreads();
    }
    if (t == 0) ws[WS_CNORM + k] = red[0];
  } else {
    int b = blockIdx.x - 512;
    unsigned short* zb0 = (unsigned short*)(ws + WS_ZB);
    unsigned short* zb1 = zb0 + ZB_STRIDE;
    float part = 0.f;
    for (int d = t; d < Dsz; d += 256) {
      float m = mu[b * Dsz + d];
      float s = expf(ls[b * Dsz + d]);
      zb0[(size_t)b * 512 + d] = f2bf(m);
      zb1[(size_t)b * 512 + d] = f2bf(s);
      part += m * m + s * s;
    }
    red[t] = part;
    __syncthreads();
    for (int off = 128; off > 0; off >>= 1) {
      if (t < off) red[t] += red[t + off];
      __syncthreads();
    }
    if (t == 0) ws[WS_BNORM + b] = red[0];
  }
}

// ---------- K2: d_kb via bf16 MFMA (unchanged from R4) ----------
__global__ __launch_bounds__(256) void k_dkb(float* __restrict__ ws,
                                             float* __restrict__ out) {
  __shared__ float pl[4][16][33];
  int t = threadIdx.x, l = t & 63, w = t >> 6;
  int lr = l & 15, lh = l >> 4;
  if (blockIdx.x == 0) out[OUT_DIST + t] = 0.f;
  int kt = blockIdx.x >> 3, bt = blockIdx.x & 7;
  int k0 = kt * 16, b0 = bt * 32;
  const unsigned short* Ap =
      (const unsigned short*)(ws + WS_ONB) + (size_t)(w >> 1) * ONB_STRIDE + (size_t)k0 * 512;
  const unsigned short* Bp =
      (const unsigned short*)(ws + WS_ZB) + (size_t)(w >> 1) * ZB_STRIDE + (size_t)b0 * 512;
  int dbase = (w & 1) * 256;

  f32x4 acc[2];
#pragma unroll
  for (int j = 0; j < 2; ++j) { acc[j][0] = 0.f; acc[j][1] = 0.f; acc[j][2] = 0.f; acc[j][3] = 0.f; }

#pragma unroll
  for (int kk = 0; kk < 8; ++kk) {
    int dl = dbase + kk * 32 + lh * 8;
    bf16x8 a0 = *(const bf16x8*)(Ap + (size_t)lr * 512 + dl);
    bf16x8 q0 = *(const bf16x8*)(Bp + (size_t)lr * 512 + dl);
    bf16x8 q1 = *(const bf16x8*)(Bp + (size_t)(lr + 16) * 512 + dl);
    acc[0] = __builtin_amdgcn_mfma_f32_16x16x32_bf16(a0, q0, acc[0], 0, 0, 0);
    acc[1] = __builtin_amdgcn_mfma_f32_16x16x32_bf16(a0, q1, acc[1], 0, 0, 0);
  }

#pragma unroll
  for (int j = 0; j < 2; ++j)
#pragma unroll
    for (int r = 0; r < 4; ++r)
      pl[w][lh * 4 + r][j * 16 + lr] = acc[j][r];
  __syncthreads();

  int r = t >> 4, c = (t & 15) * 2;
  float s0 = pl[0][r][c] + pl[1][r][c] + pl[2][r][c] + pl[3][r][c];
  float s1 = pl[0][r][c + 1] + pl[1][r][c + 1] + pl[2][r][c + 1] + pl[3][r][c + 1];
  float cn = ws[WS_CNORM + k0 + r];
  float2 o = make_float2(cn + ws[WS_BNORM + b0 + c] - 2.f * s0,
                         cn + ws[WS_BNORM + b0 + c + 1] - 2.f * s1);
  *(float2*)&ws[WS_DFLAT + (size_t)(k0 + r) * 256 + b0 + c] = o;
}

// ---------- K3: fused softmaxes + dist atomics; psb in fragment order ----------
__global__ __launch_bounds__(256) void k_sm(float* __restrict__ ws,
                                            float* __restrict__ out) {
  int g = blockIdx.x, t = threadIdx.x;
  const float* df = ws + WS_DFLAT;
  int k = 2 * t + (g >> 5);
  int col = (g & 31) << 3;
  const float* p = df + (size_t)k * 256 + col;
  float4 v0 = *(const float4*)p;
  float4 v1 = *(const float4*)(p + 4);
  float d[8] = {v0.x, v0.y, v0.z, v0.w, v1.x, v1.y, v1.z, v1.w};
  float m = d[0];
#pragma unroll
  for (int n = 1; n < 8; ++n) m = fminf(m, d[n]);
  float wv[8], s = 0.f, wd = 0.f;
#pragma unroll
  for (int n = 0; n < 8; ++n) {
    wv[n] = expf(m - d[n]);
    s += wv[n];
    wd += wv[n] * d[n];
  }
  float inv = 1.f / s;
  float* so = ws + WS_SOFTS + (size_t)t * 512 + g * 8;
  *(float4*)so = make_float4(wv[0] * inv, wv[1] * inv, wv[2] * inv, wv[3] * inv);
  *(float4*)(so + 4) = make_float4(wv[4] * inv, wv[5] * inv, wv[6] * inv, wv[7] * inv);
  float dbg = wd * inv;
  out[OUT_DBG + t * 64 + g] = dbg;

  __shared__ float red[256];
  red[t] = dbg;
  __syncthreads();
  for (int off = 128; off > 0; off >>= 1) {
    if (t < off) red[t] = fminf(red[t], red[t + off]);
    __syncthreads();
  }
  float mm = red[0];
  __syncthreads();
  float wp = expf(mm - dbg);
  red[t] = wp;
  __syncthreads();
  for (int off = 128; off > 0; off >>= 1) {
    if (t < off) red[t] += red[t + off];
    __syncthreads();
  }
  float psv = wp / red[0];
  ((unsigned short*)(ws + WS_PSB))[psb_idx(t, g)] = f2bf(psv);
  atomicAdd(&out[OUT_DIST + t], psv * dbg);
}

// ---------- K4a: states GEMMs. S[g][x][e*512+d] = sum_n softs[x][g*8+n]*onb_e[g*8+n][d].
// grid 256 = g(64) x xq(4). onb read ONCE total (1 MB), S written once (33.5 MB bf16). ----------
__global__ __launch_bounds__(256) void k_states(float* __restrict__ ws) {
  __shared__ __align__(16) unsigned short ol[8192];  // [ed 1024][n 8] bf16, XOR-swizzled
  int g = blockIdx.x >> 2, xq = blockIdx.x & 3;
  int t = threadIdx.x;
  // stage 16 rows (2e x 8n) x 512 d, transposed into ol
  {
    int row = t >> 4, e = row >> 3, n = row & 7;
    int d0 = (t & 15) * 32;
    const unsigned short* src = (const unsigned short*)(ws + WS_ONB) +
                                (size_t)e * ONB_STRIDE + (size_t)(g * 8 + n) * 512 + d0;
#pragma unroll
    for (int q = 0; q < 4; ++q) {
      bf16x8 v = *(const bf16x8*)(src + q * 8);
#pragma unroll
      for (int i = 0; i < 8; ++i) {
        int ed = e * 512 + d0 + q * 8 + i;
        ol[(ed * 8 + n) ^ (((ed >> 6) & 15) << 3)] = (unsigned short)v[i];
      }
    }
  }
  // softs for this thread's 4 x's into regs
  int edg = t & 15, xg = t >> 4;
  float sf[4][8];
#pragma unroll
  for (int xi = 0; xi < 4; ++xi) {
    int x = xq * 64 + xg * 4 + xi;
    float4 s0 = *(const float4*)&ws[WS_SOFTS + (size_t)x * 512 + g * 8];
    float4 s1 = *(const float4*)&ws[WS_SOFTS + (size_t)x * 512 + g * 8 + 4];
    sf[xi][0] = s0.x; sf[xi][1] = s0.y; sf[xi][2] = s0.z; sf[xi][3] = s0.w;
    sf[xi][4] = s1.x; sf[xi][5] = s1.y; sf[xi][6] = s1.z; sf[xi][7] = s1.w;
  }
  __syncthreads();

  unsigned short* Sp = (unsigned short*)(ws + WS_S);
#pragma unroll 1
  for (int cb = 0; cb < 8; ++cb) {
    bf16x8 op[4];
#pragma unroll
    for (int cc = 0; cc < 8; ++cc) {
      int ed = edg * 64 + cb * 8 + cc;
      bf16x8 v = *(const bf16x8*)&ol[(ed * 8) ^ (((ed >> 6) & 15) << 3)];
      float vf[8];
#pragma unroll
      for (int n = 0; n < 8; ++n) vf[n] = bf2f((unsigned short)v[n]);
#pragma unroll
      for (int xi = 0; xi < 4; ++xi) {
        float a = 0.f;
#pragma unroll
        for (int n = 0; n < 8; ++n) a += sf[xi][n] * vf[n];
        op[xi][cc] = (short)f2bf(a);
      }
    }
#pragma unroll
    for (int xi = 0; xi < 4; ++xi) {
      size_t idx = ((size_t)g * 256 + xq * 64 + xg * 4 + xi) * 1024 + edg * 64 + cb * 8;
      *(bf16x8*)&Sp[idx] = op[xi];
    }
  }
}

// ---------- K5 (split): near-pure write kernel. grid 2048 = x(256) x dt(8). ----------
__global__ __launch_bounds__(256) void k_quant_s(const float* __restrict__ ws,
                                                 float* __restrict__ out) {
  __shared__ __align__(16) unsigned short st[8192];  // [d64][e2][g64] swizzled, 16 KB
  int x = blockIdx.x >> 3, dt = blockIdx.x & 7;
  int dBase = dt * 64;
  int t = threadIdx.x, l = t & 63, w = t >> 6;
  int lr = l & 15, lh = l >> 4;

  // bn frags: fragment-order psb -> fully coalesced (l*8)
  const unsigned short* psb = (const unsigned short*)(ws + WS_PSB);
  bf16x8 bn[4][2];
#pragma unroll
  for (int j = 0; j < 4; ++j)
#pragma unroll
    for (int kk = 0; kk < 2; ++kk)
      bn[j][kk] = *(const bf16x8*)&psb[w * 4096 + j * 1024 + kk * 512 + l * 8];

  // stage S slice (16 KB) with transpose into st
  {
    int gp = t >> 2, e = (t >> 1) & 1, half = t & 1;
    const unsigned short* s0 = (const unsigned short*)(ws + WS_S) +
                               ((size_t)(gp * 2) * 256 + x) * 1024 + e * 512 + dBase + half * 32;
    const unsigned short* s1 = s0 + 262144;  // +1 g
#pragma unroll
    for (int q = 0; q < 4; ++q) {
      bf16x8 v0 = *(const bf16x8*)(s0 + q * 8);
      bf16x8 v1 = *(const bf16x8*)(s1 + q * 8);
#pragma unroll
      for (int i = 0; i < 8; ++i) {
        int d = half * 32 + q * 8 + i;
        ushort2 pr = make_ushort2((unsigned short)v0[i], (unsigned short)v1[i]);
        *(ushort2*)&st[d * 128 + e * 64 + ((gp * 2) ^ ((d & 7) << 3))] = pr;
      }
    }
  }
  __syncthreads();

#pragma unroll 1
  for (int e = 0; e < 2; ++e) {
    bf16x8 am[4][2];
#pragma unroll
    for (int i = 0; i < 4; ++i)
#pragma unroll
      for (int kk = 0; kk < 2; ++kk)
        am[i][kk] = *(const bf16x8*)&st[(i * 16 + lr) * 128 + e * 64 +
                                        ((kk * 32 + lh * 8) ^ ((lr & 7) << 3))];

    f32x4 acc[4][4];
#pragma unroll
    for (int i = 0; i < 4; ++i)
#pragma unroll
      for (int j = 0; j < 4; ++j) {
        acc[i][j][0] = 0.f; acc[i][j][1] = 0.f; acc[i][j][2] = 0.f; acc[i][j][3] = 0.f;
      }
#pragma unroll
    for (int kk = 0; kk < 2; ++kk)
#pragma unroll
      for (int i = 0; i < 4; ++i)
#pragma unroll
        for (int j = 0; j < 4; ++j)
          acc[i][j] = __builtin_amdgcn_mfma_f32_16x16x32_bf16(am[i][kk], bn[j][kk], acc[i][j], 0, 0, 0);

    float* op = out + (e ? (size_t)OUT_QSIG : (size_t)OUT_QMU) + (size_t)x * (256 * 512);
#pragma unroll
    for (int i = 0; i < 4; ++i)
#pragma unroll
      for (int j = 0; j < 4; ++j) {
        size_t off = (size_t)(w * 64 + j * 16 + lr) * 512 + dBase + i * 16 + lh * 4;
        *(f32x4*)&op[off] = acc[i][j];
      }
  }
}

// ---------- K5 (fallback, ws too small): R4 k_quant + fragment-order bn ----------
__global__ __launch_bounds__(256) void k_quant_f(const float* __restrict__ ws,
                                                 float* __restrict__ out) {
  __shared__ __align__(16) unsigned short st[2][4096];
  __shared__ float sxl[576];
  int x = blockIdx.x >> 3, dt = blockIdx.x & 7;
  int dBase = dt * 64;
  int t = threadIdx.x, l = t & 63, w = t >> 6;
  int lr = l & 15, lh = l >> 4;

  const unsigned short* psb = (const unsigned short*)(ws + WS_PSB);
  bf16x8 bn[4][2];
#pragma unroll
  for (int j = 0; j < 4; ++j)
#pragma unroll
    for (int kk = 0; kk < 2; ++kk)
      bn[j][kk] = *(const bf16x8*)&psb[w * 4096 + j * 1024 + kk * 512 + l * 8];

  {
    int i0 = t, i1 = t + 256;
    sxl[(i0 >> 3) * 9 + (i0 & 7)] = ws[WS_SOFTS + (size_t)x * 512 + i0];
    sxl[(i1 >> 3) * 9 + (i1 & 7)] = ws[WS_SOFTS + (size_t)x * 512 + 256 + i0];
  }
  __syncthreads();

  int dq = t & 15, gq = t >> 4;
#pragma unroll 1
  for (int e = 0; e < 2; ++e) {
    const unsigned short* ob =
        (const unsigned short*)(ws + WS_ONB) + (size_t)e * ONB_STRIDE + dBase + dq * 4;
    float av[4][4];
#pragma unroll
    for (int gg = 0; gg < 4; ++gg) {
      int g = gq * 4 + gg;
      float a0 = 0.f, a1 = 0.f, a2 = 0.f, a3 = 0.f;
      const unsigned short* rp = ob + (size_t)(g * 8) * 512;
#pragma unroll
      for (int n = 0; n < 8; ++n) {
        ushort4 vv = *(const ushort4*)(rp + (size_t)n * 512);
        float swv = sxl[g * 9 + n];
        a0 += swv * bf2f(vv.x);
        a1 += swv * bf2f(vv.y);
        a2 += swv * bf2f(vv.z);
        a3 += swv * bf2f(vv.w);
      }
      av[gg][0] = a0; av[gg][1] = a1; av[gg][2] = a2; av[gg][3] = a3;
    }
#pragma unroll
    for (int dd = 0; dd < 4; ++dd) {
      int d = dq * 4 + dd;
      ushort4 o = make_ushort4(f2bf(av[0][dd]), f2bf(av[1][dd]), f2bf(av[2][dd]), f2bf(av[3][dd]));
      *(ushort4*)&st[e][(d * 64 + gq * 4) ^ ((d & 7) << 3)] = o;
    }
  }
  __syncthreads();

#pragma unroll 1
  for (int e = 0; e < 2; ++e) {
    bf16x8 am[4][2];
#pragma unroll
    for (int i = 0; i < 4; ++i)
#pragma unroll
      for (int kk = 0; kk < 2; ++kk)
        am[i][kk] = *(const bf16x8*)&st[e][((i * 16 + lr) * 64 + kk * 32 + lh * 8) ^ ((lr & 7) << 3)];

    f32x4 acc[4][4];
#pragma unroll
    for (int i = 0; i < 4; ++i)
#pragma unroll
      for (int j = 0; j < 4; ++j) {
        acc[i][j][0] = 0.f; acc[i][j][1] = 0.f; acc[i][j][2] = 0.f; acc[i][j][3] = 0.f;
      }
#pragma unroll
    for (int kk = 0; kk < 2; ++kk)
#pragma unroll
      for (int i = 0; i < 4; ++i)
#pragma unroll
        for (int j = 0; j < 4; ++j)
          acc[i][j] = __builtin_amdgcn_mfma_f32_16x16x32_bf16(am[i][kk], bn[j][kk], acc[i][j], 0, 0, 0);

    float* op = out + (e ? (size_t)OUT_QSIG : (size_t)OUT_QMU) + (size_t)x * (256 * 512);
#pragma unroll
    for (int i = 0; i < 4; ++i)
#pragma unroll
      for (int j = 0; j < 4; ++j) {
        size_t off = (size_t)(w * 64 + j * 16 + lr) * 512 + dBase + i * 16 + lh * 4;
        *(f32x4*)&op[off] = acc[i][j];
      }
  }
}

extern "C" void kernel_launch(void* const* d_in, const int* in_sizes, int n_in,
                              void* d_out, int out_size, void* d_ws, size_t ws_size,
                              hipStream_t stream) {
  (void)in_sizes; (void)n_in; (void)out_size;
  const float* mu = (const float*)d_in[0];
  const float* ls = (const float*)d_in[1];
  const float* on = (const float*)d_in[2];
  float* out = (float*)d_out;
  float* ws = (float*)d_ws;

  k_prep<<<dim3(768), dim3(256), 0, stream>>>(mu, ls, on, ws);
  k_dkb<<<dim3(256), dim3(256), 0, stream>>>(ws, out);
  k_sm<<<dim3(64), dim3(256), 0, stream>>>(ws, out);
  if (ws_size >= WS_S_NEED) {
    k_states<<<dim3(256), dim3(256), 0, stream>>>(ws);
    k_quant_s<<<dim3(2048), dim3(256), 0, stream>>>(ws, out);
  } else {
    k_quant_f<<<dim3(2048), dim3(256), 0, stream>>>(ws, out);
  }
}

// Round 7
// 75.301 us; speedup vs baseline: 1.7007x; 1.6499x over previous
//
#include <hip/hip_runtime.h>
#include <cstddef>
#include <cstdint>

typedef short bf16x8 __attribute__((ext_vector_type(8)));
typedef float f32x4 __attribute__((ext_vector_type(4)));

#define Bsz 256
#define Dsz 512
#define Gsz 64
#define Ksz 512

// ws float offsets
#define WS_DFLAT 0         // [512][256] f32
#define WS_SOFTS 131072    // [256][512] f32 (b-major, flat-k)
#define WS_BNORM 278528    // [256]
#define WS_CNORM 278784    // [512]
#define WS_PSB   279296    // [256][64] bf16
#define WS_ONB   287488    // 2 planes [512][512] bf16
#define WS_ZB    549632    // 2 planes [256][512] bf16

#define ONB_STRIDE 262144  // ushorts per plane
#define ZB_STRIDE  131072  // ushorts per plane

// out float offsets
#define OUT_QMU  0
#define OUT_QSIG 33554432
#define OUT_DBG  67108864
#define OUT_DIST 67125248

__device__ __forceinline__ unsigned short f2bf(float f) {
  unsigned int u = __float_as_uint(f);
  u = (u + 0x7FFFu + ((u >> 16) & 1u)) >> 16;
  return (unsigned short)u;
}
__device__ __forceinline__ float bf2f(unsigned short h) {
  return __uint_as_float(((unsigned int)h) << 16);
}

// ---------- K1: prep (proven R2/R4) ----------
__global__ __launch_bounds__(256) void k_prep(const float* __restrict__ mu,
                                              const float* __restrict__ ls,
                                              const float* __restrict__ on,
                                              float* __restrict__ ws) {
  int t = threadIdx.x;
  __shared__ float red[256];
  if (blockIdx.x < 512) {
    int k = blockIdx.x;
    float4 v = *(const float4*)(on + (size_t)k * 1024 + 4 * t);
    unsigned short* onb0 = (unsigned short*)(ws + WS_ONB);
    unsigned short* onb1 = onb0 + ONB_STRIDE;
    *(ushort2*)&onb0[(size_t)k * 512 + 2 * t] = make_ushort2(f2bf(v.x), f2bf(v.z));
    *(ushort2*)&onb1[(size_t)k * 512 + 2 * t] = make_ushort2(f2bf(v.y), f2bf(v.w));
    red[t] = v.x * v.x + v.y * v.y + v.z * v.z + v.w * v.w;
    __syncthreads();
    for (int off = 128; off > 0; off >>= 1) {
      if (t < off) red[t] += red[t + off];
      __syncthreads();
    }
    if (t == 0) ws[WS_CNORM + k] = red[0];
  } else {
    int b = blockIdx.x - 512;
    unsigned short* zb0 = (unsigned short*)(ws + WS_ZB);
    unsigned short* zb1 = zb0 + ZB_STRIDE;
    float part = 0.f;
    for (int d = t; d < Dsz; d += 256) {
      float m = mu[b * Dsz + d];
      float s = expf(ls[b * Dsz + d]);
      zb0[(size_t)b * 512 + d] = f2bf(m);
      zb1[(size_t)b * 512 + d] = f2bf(s);
      part += m * m + s * s;
    }
    red[t] = part;
    __syncthreads();
    for (int off = 128; off > 0; off >>= 1) {
      if (t < off) red[t] += red[t + off];
      __syncthreads();
    }
    if (t == 0) ws[WS_BNORM + b] = red[0];
  }
}

// ---------- K2: d_kb via bf16 MFMA (proven R4) ----------
__global__ __launch_bounds__(256) void k_dkb(float* __restrict__ ws,
                                             float* __restrict__ out) {
  __shared__ float pl[4][16][33];
  int t = threadIdx.x, l = t & 63, w = t >> 6;
  int lr = l & 15, lh = l >> 4;
  if (blockIdx.x == 0) out[OUT_DIST + t] = 0.f;
  int kt = blockIdx.x >> 3, bt = blockIdx.x & 7;
  int k0 = kt * 16, b0 = bt * 32;
  const unsigned short* Ap =
      (const unsigned short*)(ws + WS_ONB) + (size_t)(w >> 1) * ONB_STRIDE + (size_t)k0 * 512;
  const unsigned short* Bp =
      (const unsigned short*)(ws + WS_ZB) + (size_t)(w >> 1) * ZB_STRIDE + (size_t)b0 * 512;
  int dbase = (w & 1) * 256;

  f32x4 acc[2];
#pragma unroll
  for (int j = 0; j < 2; ++j) { acc[j][0] = 0.f; acc[j][1] = 0.f; acc[j][2] = 0.f; acc[j][3] = 0.f; }

#pragma unroll
  for (int kk = 0; kk < 8; ++kk) {
    int dl = dbase + kk * 32 + lh * 8;
    bf16x8 a0 = *(const bf16x8*)(Ap + (size_t)lr * 512 + dl);
    bf16x8 q0 = *(const bf16x8*)(Bp + (size_t)lr * 512 + dl);
    bf16x8 q1 = *(const bf16x8*)(Bp + (size_t)(lr + 16) * 512 + dl);
    acc[0] = __builtin_amdgcn_mfma_f32_16x16x32_bf16(a0, q0, acc[0], 0, 0, 0);
    acc[1] = __builtin_amdgcn_mfma_f32_16x16x32_bf16(a0, q1, acc[1], 0, 0, 0);
  }

#pragma unroll
  for (int j = 0; j < 2; ++j)
#pragma unroll
    for (int r = 0; r < 4; ++r)
      pl[w][lh * 4 + r][j * 16 + lr] = acc[j][r];
  __syncthreads();

  int r = t >> 4, c = (t & 15) * 2;
  float s0 = pl[0][r][c] + pl[1][r][c] + pl[2][r][c] + pl[3][r][c];
  float s1 = pl[0][r][c + 1] + pl[1][r][c + 1] + pl[2][r][c + 1] + pl[3][r][c + 1];
  float cn = ws[WS_CNORM + k0 + r];
  float2 o = make_float2(cn + ws[WS_BNORM + b0 + c] - 2.f * s0,
                         cn + ws[WS_BNORM + b0 + c + 1] - 2.f * s1);
  *(float2*)&ws[WS_DFLAT + (size_t)(k0 + r) * 256 + b0 + c] = o;
}

// ---------- K3: fused softmaxes + dist atomics; psb NORMAL [b][g] order ----------
__global__ __launch_bounds__(256) void k_sm(float* __restrict__ ws,
                                            float* __restrict__ out) {
  int g = blockIdx.x, t = threadIdx.x;
  const float* df = ws + WS_DFLAT;
  int k = 2 * t + (g >> 5);
  int col = (g & 31) << 3;
  const float* p = df + (size_t)k * 256 + col;
  float4 v0 = *(const float4*)p;
  float4 v1 = *(const float4*)(p + 4);
  float d[8] = {v0.x, v0.y, v0.z, v0.w, v1.x, v1.y, v1.z, v1.w};
  float m = d[0];
#pragma unroll
  for (int n = 1; n < 8; ++n) m = fminf(m, d[n]);
  float wv[8], s = 0.f, wd = 0.f;
#pragma unroll
  for (int n = 0; n < 8; ++n) {
    wv[n] = expf(m - d[n]);
    s += wv[n];
    wd += wv[n] * d[n];
  }
  float inv = 1.f / s;
  float* so = ws + WS_SOFTS + (size_t)t * 512 + g * 8;
  *(float4*)so = make_float4(wv[0] * inv, wv[1] * inv, wv[2] * inv, wv[3] * inv);
  *(float4*)(so + 4) = make_float4(wv[4] * inv, wv[5] * inv, wv[6] * inv, wv[7] * inv);
  float dbg = wd * inv;
  out[OUT_DBG + t * 64 + g] = dbg;

  __shared__ float red[256];
  red[t] = dbg;
  __syncthreads();
  for (int off = 128; off > 0; off >>= 1) {
    if (t < off) red[t] = fminf(red[t], red[t + off]);
    __syncthreads();
  }
  float mm = red[0];
  __syncthreads();
  float wp = expf(mm - dbg);
  red[t] = wp;
  __syncthreads();
  for (int off = 128; off > 0; off >>= 1) {
    if (t < off) red[t] += red[t + off];
    __syncthreads();
  }
  float psv = wp / red[0];
  ((unsigned short*)(ws + WS_PSB))[t * 64 + g] = f2bf(psv);
  atomicAdd(&out[OUT_DIST + t], psv * dbg);
}

// ---------- K4: quantised_{mu,sig}. R2's psl staging + R4's single-phase
// S_T build + barrier-free MFMA/store tail (syncthreads drains vmcnt(0), so
// any barrier between store batches serializes ~20us of writes against VALU;
// here: stage->sync->build both planes->sync->mfma+store e0,e1 uninterrupted).
__global__ __launch_bounds__(256) void k_quant(const float* __restrict__ ws,
                                               float* __restrict__ out) {
  __shared__ __align__(16) unsigned short psl[16384];   // [b][g] swz, 32 KB
  __shared__ __align__(16) unsigned short st[2][4096];  // [e][d][g] swz, 16 KB
  __shared__ float sxl[576];                            // softs, stride-9 padded
  int x = blockIdx.x >> 3, dt = blockIdx.x & 7;
  int dBase = dt * 64;
  int t = threadIdx.x, l = t & 63, w = t >> 6;
  int lr = l & 15, lh = l >> 4;

  // stage ps into LDS (proven R2 pattern)
  const unsigned short* psb = (const unsigned short*)(ws + WS_PSB);
#pragma unroll
  for (int c = 0; c < 8; ++c) {
    int cc = t + c * 256;  // 0..2047 chunks of 8 ushorts
    int b = cc >> 3, gw8 = (cc & 7) * 8;
    bf16x8 v = *(const bf16x8*)(psb + (size_t)b * 64 + gw8);
    *(bf16x8*)&psl[(b * 64 + gw8) ^ ((b & 7) << 3)] = v;
  }
  {
    int i0 = t, i1 = t + 256;
    sxl[(i0 >> 3) * 9 + (i0 & 7)] = ws[WS_SOFTS + (size_t)x * 512 + i0];
    sxl[(i1 >> 3) * 9 + (i1 & 7)] = ws[WS_SOFTS + (size_t)x * 512 + i1];
  }
  __syncthreads();

  // build S_T for BOTH planes (proven R4): thread owns 4 d x 4 g
  int dq = t & 15, gq = t >> 4;
#pragma unroll 1
  for (int e = 0; e < 2; ++e) {
    const unsigned short* ob =
        (const unsigned short*)(ws + WS_ONB) + (size_t)e * ONB_STRIDE + dBase + dq * 4;
    float av[4][4];
#pragma unroll
    for (int gg = 0; gg < 4; ++gg) {
      int g = gq * 4 + gg;
      float a0 = 0.f, a1 = 0.f, a2 = 0.f, a3 = 0.f;
      const unsigned short* rp = ob + (size_t)(g * 8) * 512;
#pragma unroll
      for (int n = 0; n < 8; ++n) {
        ushort4 vv = *(const ushort4*)(rp + (size_t)n * 512);
        float swv = sxl[g * 9 + n];
        a0 += swv * bf2f(vv.x);
        a1 += swv * bf2f(vv.y);
        a2 += swv * bf2f(vv.z);
        a3 += swv * bf2f(vv.w);
      }
      av[gg][0] = a0; av[gg][1] = a1; av[gg][2] = a2; av[gg][3] = a3;
    }
#pragma unroll
    for (int dd = 0; dd < 4; ++dd) {
      int d = dq * 4 + dd;
      ushort4 o = make_ushort4(f2bf(av[0][dd]), f2bf(av[1][dd]), f2bf(av[2][dd]), f2bf(av[3][dd]));
      *(ushort4*)&st[e][(d * 64 + gq * 4) ^ ((d & 7) << 3)] = o;
    }
  }
  __syncthreads();

  // bn frags from LDS (proven R2 pattern)
  bf16x8 bn[4][2];
#pragma unroll
  for (int j = 0; j < 4; ++j)
#pragma unroll
    for (int kk = 0; kk < 2; ++kk) {
      int b = w * 64 + j * 16 + lr;
      bn[j][kk] = *(const bf16x8*)&psl[(b * 64 + kk * 32 + lh * 8) ^ ((b & 7) << 3)];
    }

  // MFMA + store, both planes, NO barriers from here on
#pragma unroll 1
  for (int e = 0; e < 2; ++e) {
    bf16x8 am[4][2];
#pragma unroll
    for (int i = 0; i < 4; ++i)
#pragma unroll
      for (int kk = 0; kk < 2; ++kk)
        am[i][kk] = *(const bf16x8*)&st[e][((i * 16 + lr) * 64 + kk * 32 + lh * 8) ^ ((lr & 7) << 3)];

    f32x4 acc[4][4];
#pragma unroll
    for (int i = 0; i < 4; ++i)
#pragma unroll
      for (int j = 0; j < 4; ++j) {
        acc[i][j][0] = 0.f; acc[i][j][1] = 0.f; acc[i][j][2] = 0.f; acc[i][j][3] = 0.f;
      }
#pragma unroll
    for (int kk = 0; kk < 2; ++kk)
#pragma unroll
      for (int i = 0; i < 4; ++i)
#pragma unroll
        for (int j = 0; j < 4; ++j)
          acc[i][j] = __builtin_amdgcn_mfma_f32_16x16x32_bf16(am[i][kk], bn[j][kk], acc[i][j], 0, 0, 0);

    float* op = out + (e ? (size_t)OUT_QSIG : (size_t)OUT_QMU) + (size_t)x * (256 * 512);
#pragma unroll
    for (int i = 0; i < 4; ++i)
#pragma unroll
      for (int j = 0; j < 4; ++j) {
        size_t off = (size_t)(w * 64 + j * 16 + lr) * 512 + dBase + i * 16 + lh * 4;
        *(f32x4*)&op[off] = acc[i][j];
      }
  }
}

extern "C" void kernel_launch(void* const* d_in, const int* in_sizes, int n_in,
                              void* d_out, int out_size, void* d_ws, size_t ws_size,
                              hipStream_t stream) {
  (void)in_sizes; (void)n_in; (void)out_size; (void)ws_size;
  const float* mu = (const float*)d_in[0];
  const float* ls = (const float*)d_in[1];
  const float* on = (const float*)d_in[2];
  float* out = (float*)d_out;
  float* ws = (float*)d_ws;

  k_prep<<<dim3(768), dim3(256), 0, stream>>>(mu, ls, on, ws);
  k_dkb<<<dim3(256), dim3(256), 0, stream>>>(ws, out);
  k_sm<<<dim3(64), dim3(256), 0, stream>>>(ws, out);
  k_quant<<<dim3(2048), dim3(256), 0, stream>>>(ws, out);
}